// Round 1
// baseline (1087.966 us; speedup 1.0000x reference)
//
#include <hip/hip_runtime.h>

typedef _Float16 half_t;
typedef _Float16 half8  __attribute__((ext_vector_type(8)));
typedef _Float16 half4v __attribute__((ext_vector_type(4)));
typedef float    f32x4  __attribute__((ext_vector_type(4)));

#define AS1 __attribute__((address_space(1)))
#define AS3 __attribute__((address_space(3)))

#define MODE_H16  0   // store fp16
#define MODE_F32R 1   // store fp32 = acc + bias + residual
#define MODE_GELU 2   // store fp16 = gelu(acc + bias)
#define MODE_VT   3   // store fp16 transposed: out[b][col][s]  (V^T for attention)

__device__ __forceinline__ f32x4 zero4() {
    f32x4 z; z[0] = 0.f; z[1] = 0.f; z[2] = 0.f; z[3] = 0.f; return z;
}

__device__ __forceinline__ half8 lds_frag(const half_t* p) {
    union { uint4 u; half8 h; } c;
    c.u = *(const uint4*)p;
    return c.h;
}

// async global->LDS, 16B/lane; LDS dest is wave-uniform base + lane*16
__device__ __forceinline__ void gl_lds16(const half_t* g, half_t* l) {
    __builtin_amdgcn_global_load_lds(
        (AS1 unsigned int*)(unsigned long long)(const void*)g,
        (AS3 unsigned int*)l,
        16, 0, 0);
}

// ---------------------------------------------------------------------------
// C[M,N] = A[M,K] @ Bt[N,K]^T + bias, fused epilogues. 128x128 tile, BK=32.
// ---------------------------------------------------------------------------
__global__ __launch_bounds__(256) void gemm_bt(
    const half_t* __restrict__ A,
    const half_t* __restrict__ Bt,
    const float*  __restrict__ bias,
    const float*  __restrict__ res,
    void* __restrict__ out,
    int M, int N, int K, int mode)
{
    __shared__ __align__(16) half_t As[128 * 32];
    __shared__ __align__(16) half_t Bs[128 * 32];

    const int tid  = threadIdx.x;
    const int w    = tid >> 6, lane = tid & 63;
    const int m0   = blockIdx.y * 128, n0 = blockIdx.x * 128;
    const int lr   = lane >> 2;        // 0..15: row within 16-row staging group
    const int lc   = (lane & 3) * 8;   // k offset within BK
    const int g    = lane >> 4, ml = lane & 15;
    const int mo   = (w >> 1) * 64, no = (w & 1) * 64;

    f32x4 acc[4][4];
#pragma unroll
    for (int i = 0; i < 4; i++)
#pragma unroll
        for (int j = 0; j < 4; j++) acc[i][j] = zero4();

    const half_t* Ag = A  + (size_t)m0 * K;
    const half_t* Bg = Bt + (size_t)n0 * K;

    for (int k0 = 0; k0 < K; k0 += 32) {
        __syncthreads();
#pragma unroll
        for (int i = 0; i < 2; i++) {
            int r = (w * 2 + i) * 16 + lr;
            gl_lds16(Ag + (size_t)r * K + k0 + lc, &As[(w * 2 + i) * 512]);
            gl_lds16(Bg + (size_t)r * K + k0 + lc, &Bs[(w * 2 + i) * 512]);
        }
        __syncthreads();

        half8 af[4], bf[4];
#pragma unroll
        for (int i = 0; i < 4; i++) af[i] = lds_frag(&As[(mo + i * 16 + ml) * 32 + g * 8]);
#pragma unroll
        for (int j = 0; j < 4; j++) bf[j] = lds_frag(&Bs[(no + j * 16 + ml) * 32 + g * 8]);
#pragma unroll
        for (int i = 0; i < 4; i++)
#pragma unroll
            for (int j = 0; j < 4; j++)
                acc[i][j] = __builtin_amdgcn_mfma_f32_16x16x32_f16(af[i], bf[j], acc[i][j], 0, 0, 0);
    }

    const int gm0 = m0 + mo, gn0 = n0 + no;
#pragma unroll
    for (int j = 0; j < 4; j++) {
        int col = gn0 + j * 16 + ml;
        float bv = bias[col];
#pragma unroll
        for (int i = 0; i < 4; i++) {
#pragma unroll
            for (int r = 0; r < 4; r++) {
                int row = gm0 + i * 16 + g * 4 + r;
                float v = acc[i][j][r] + bv;
                size_t idx = (size_t)row * N + col;
                if (mode == MODE_F32R) {
                    ((float*)out)[idx] = v + res[idx];
                } else if (mode == MODE_GELU) {
                    v = 0.5f * v * (1.f + erff(v * 0.70710678118654752f));
                    ((half_t*)out)[idx] = (half_t)v;
                } else if (mode == MODE_VT) {
                    int bb = row >> 11, sl = row & 2047;    // S = 2048
                    ((half_t*)out)[((size_t)bb * N + col) * 2048 + sl] = (half_t)v;
                } else {
                    ((half_t*)out)[idx] = (half_t)v;
                }
            }
        }
    }
}

// ---------------------------------------------------------------------------
// Flash attention: 64 q-rows per block (4 waves x 16 rows), K-tiles of 64.
// Q,K: [B*S][H] fp16 ; Vt: [B][H][S] fp16 ; ctx out: [B*S][H] fp16.
// ---------------------------------------------------------------------------
__global__ __launch_bounds__(256) void flash_attn(
    const half_t* __restrict__ Q,
    const half_t* __restrict__ Kq,
    const half_t* __restrict__ Vt,
    const float*  __restrict__ mask,   // [B*S] additive
    half_t* __restrict__ ctx,
    int S, int H)
{
    __shared__ __align__(16) half_t Qs[64 * 72];
    __shared__ __align__(16) half_t Ks[64 * 72];
    __shared__ __align__(16) half_t Vs[64 * 72];       // Vt tile: [d][kpos]
    __shared__ __align__(16) half_t Ps[4 * 16 * 72];   // per-wave P

    const int qt = blockIdx.x, h = blockIdx.y, b = blockIdx.z;
    const int tid = threadIdx.x, w = tid >> 6, lane = tid & 63;
    const int g = lane >> 4, ml = lane & 15;

    const half_t* Qg = Q  + ((size_t)(b * S + qt * 64)) * H + h * 64;
    const half_t* Kg = Kq + ((size_t)(b * S)) * H + h * 64;
    const half_t* Vg = Vt + ((size_t)(b * H + h * 64)) * S;
    const float*  mk = mask + (size_t)b * S;

    for (int ci = tid; ci < 512; ci += 256) {
        int r = ci >> 3, c = (ci & 7) * 8;
        *(uint4*)&Qs[r * 72 + c] = *(const uint4*)&Qg[(size_t)r * H + c];
    }
    __syncthreads();
    half8 qf0 = lds_frag(&Qs[(w * 16 + ml) * 72 + 0  + g * 8]);
    half8 qf1 = lds_frag(&Qs[(w * 16 + ml) * 72 + 32 + g * 8]);

    float mrow[4] = {-1e30f, -1e30f, -1e30f, -1e30f};
    float lrow[4] = {0.f, 0.f, 0.f, 0.f};
    f32x4 o[4];
#pragma unroll
    for (int j = 0; j < 4; j++) o[j] = zero4();
    half_t* Pw = &Ps[w * 16 * 72];

    for (int kv0 = 0; kv0 < S; kv0 += 64) {
        __syncthreads();
        for (int ci = tid; ci < 512; ci += 256) {
            int r = ci >> 3, c = (ci & 7) * 8;
            *(uint4*)&Ks[r * 72 + c] = *(const uint4*)&Kg[(size_t)(kv0 + r) * H + c];
            *(uint4*)&Vs[r * 72 + c] = *(const uint4*)&Vg[(size_t)r * S + kv0 + c];
        }
        __syncthreads();

        f32x4 s[4];
#pragma unroll
        for (int j = 0; j < 4; j++) {
            half8 k0 = lds_frag(&Ks[(j * 16 + ml) * 72 + 0  + g * 8]);
            half8 k1 = lds_frag(&Ks[(j * 16 + ml) * 72 + 32 + g * 8]);
            s[j] = __builtin_amdgcn_mfma_f32_16x16x32_f16(qf0, k0, zero4(), 0, 0, 0);
            s[j] = __builtin_amdgcn_mfma_f32_16x16x32_f16(qf1, k1, s[j],   0, 0, 0);
        }
#pragma unroll
        for (int j = 0; j < 4; j++) {
            float mval = mk[kv0 + j * 16 + ml];
#pragma unroll
            for (int r = 0; r < 4; r++) s[j][r] = s[j][r] * 0.125f + mval;
        }
#pragma unroll
        for (int r = 0; r < 4; r++) {
            float mx = fmaxf(fmaxf(s[0][r], s[1][r]), fmaxf(s[2][r], s[3][r]));
            mx = fmaxf(mx, __shfl_xor(mx, 1));
            mx = fmaxf(mx, __shfl_xor(mx, 2));
            mx = fmaxf(mx, __shfl_xor(mx, 4));
            mx = fmaxf(mx, __shfl_xor(mx, 8));
            float mnew  = fmaxf(mrow[r], mx);
            float alpha = __expf(mrow[r] - mnew);
            float ps = 0.f;
#pragma unroll
            for (int j = 0; j < 4; j++) { float p = __expf(s[j][r] - mnew); s[j][r] = p; ps += p; }
            ps += __shfl_xor(ps, 1); ps += __shfl_xor(ps, 2);
            ps += __shfl_xor(ps, 4); ps += __shfl_xor(ps, 8);
            lrow[r] = lrow[r] * alpha + ps;
            mrow[r] = mnew;
#pragma unroll
            for (int j = 0; j < 4; j++) o[j][r] = o[j][r] * alpha;
        }
        // P: C-layout -> LDS (per-wave region; same-wave RAW handled by lgkmcnt)
#pragma unroll
        for (int j = 0; j < 4; j++)
#pragma unroll
            for (int r = 0; r < 4; r++)
                Pw[(g * 4 + r) * 72 + j * 16 + ml] = (half_t)s[j][r];
#pragma unroll
        for (int kk = 0; kk < 2; kk++) {
            half8 pa = lds_frag(&Pw[ml * 72 + kk * 32 + g * 8]);
#pragma unroll
            for (int jd = 0; jd < 4; jd++) {
                half8 vb = lds_frag(&Vs[(jd * 16 + ml) * 72 + kk * 32 + g * 8]);
                o[jd] = __builtin_amdgcn_mfma_f32_16x16x32_f16(pa, vb, o[jd], 0, 0, 0);
            }
        }
    }

#pragma unroll
    for (int r = 0; r < 4; r++) {
        float inv = 1.f / lrow[r];
        int row = b * S + qt * 64 + w * 16 + g * 4 + r;
#pragma unroll
        for (int jd = 0; jd < 4; jd++)
            ctx[(size_t)row * H + h * 64 + jd * 16 + ml] = (half_t)(o[jd][r] * inv);
    }
}

// ---------------------------------------------------------------------------
// W[K][N] fp32 -> Wt[N][K] fp16 (32x32 tiles through LDS)
// ---------------------------------------------------------------------------
__global__ __launch_bounds__(256) void transpose_cast(
    const float* __restrict__ W, half_t* __restrict__ Wt, int Kd, int Nd)
{
    __shared__ float tile[32][33];
    int n0 = blockIdx.x * 32, k0 = blockIdx.y * 32;
    int tx = threadIdx.x & 31, ty = threadIdx.x >> 5;
#pragma unroll
    for (int j = 0; j < 4; j++)
        tile[ty + j * 8][tx] = W[(size_t)(k0 + ty + j * 8) * Nd + n0 + tx];
    __syncthreads();
#pragma unroll
    for (int j = 0; j < 4; j++)
        Wt[(size_t)(n0 + ty + j * 8) * Kd + k0 + tx] = (half_t)tile[tx][ty + j * 8];
}

__global__ __launch_bounds__(256) void cast_f32_f16(
    const float* __restrict__ in, half_t* __restrict__ out)
{
    int i = blockIdx.x * 256 + threadIdx.x;
    float4 v = ((const float4*)in)[i];
    half4v o; o[0] = (half_t)v.x; o[1] = (half_t)v.y; o[2] = (half_t)v.z; o[3] = (half_t)v.w;
    *(half4v*)(out + (size_t)i * 4) = o;
}

// ---------------------------------------------------------------------------
// LayerNorm over H=1024; emits fp32 (residual path) + fp16 (next GEMM input)
// ---------------------------------------------------------------------------
__global__ __launch_bounds__(256) void layernorm_k(
    const float* __restrict__ in,
    const float* __restrict__ gam, const float* __restrict__ bet,
    float* __restrict__ outf, half_t* __restrict__ outh)
{
    int row = blockIdx.x, tid = threadIdx.x;
    const float4 v = ((const float4*)(in + (size_t)row * 1024))[tid];
    float s = v.x + v.y + v.z + v.w;
    float q = v.x * v.x + v.y * v.y + v.z * v.z + v.w * v.w;
    for (int off = 32; off; off >>= 1) { s += __shfl_down(s, off); q += __shfl_down(q, off); }
    __shared__ float ss[4], sq[4];
    int w = tid >> 6;
    if ((tid & 63) == 0) { ss[w] = s; sq[w] = q; }
    __syncthreads();
    float S_ = ss[0] + ss[1] + ss[2] + ss[3];
    float Q_ = sq[0] + sq[1] + sq[2] + sq[3];
    float mean = S_ * (1.f / 1024.f);
    float var  = Q_ * (1.f / 1024.f) - mean * mean;
    float rstd = rsqrtf(var + 1e-5f);
    float4 gm = ((const float4*)gam)[tid];
    float4 bt = ((const float4*)bet)[tid];
    float y0 = (v.x - mean) * rstd * gm.x + bt.x;
    float y1 = (v.y - mean) * rstd * gm.y + bt.y;
    float y2 = (v.z - mean) * rstd * gm.z + bt.z;
    float y3 = (v.w - mean) * rstd * gm.w + bt.w;
    ((float4*)(outf + (size_t)row * 1024))[tid] = make_float4(y0, y1, y2, y3);
    half4v oh; oh[0] = (half_t)y0; oh[1] = (half_t)y1; oh[2] = (half_t)y2; oh[3] = (half_t)y3;
    *(half4v*)(outh + (size_t)row * 1024 + tid * 4) = oh;
}

// ---------------------------------------------------------------------------
extern "C" void kernel_launch(void* const* d_in, const int* in_sizes, int n_in,
                              void* d_out, int out_size, void* d_ws, size_t ws_size,
                              hipStream_t stream)
{
    const int Lc = 2, Bb = 2, S = 2048, Hh = 1024, NH = 16, FF = 4096;
    const int M = Bb * S;  // 4096

    const float* hs   = (const float*)d_in[0];
    const float* mask = (const float*)d_in[1];
    const float* Wq   = (const float*)d_in[2];  const float* bq  = (const float*)d_in[3];
    const float* Wk   = (const float*)d_in[4];  const float* bk  = (const float*)d_in[5];
    const float* Wv   = (const float*)d_in[6];  const float* bv  = (const float*)d_in[7];
    const float* Wao  = (const float*)d_in[8];  const float* bao = (const float*)d_in[9];
    const float* g1   = (const float*)d_in[10]; const float* b1  = (const float*)d_in[11];
    const float* Wi   = (const float*)d_in[12]; const float* bi  = (const float*)d_in[13];
    const float* Wo   = (const float*)d_in[14]; const float* bo  = (const float*)d_in[15];
    const float* g2   = (const float*)d_in[16]; const float* b2  = (const float*)d_in[17];

    char* p = (char*)d_ws;
    auto take = [&](size_t bytes) { char* r = p; p += (bytes + 255) & ~(size_t)255; return r; };

    half_t* WqT  = (half_t*)take((size_t)Lc * Hh * Hh * 2);
    half_t* WkT  = (half_t*)take((size_t)Lc * Hh * Hh * 2);
    half_t* WvT  = (half_t*)take((size_t)Lc * Hh * Hh * 2);
    half_t* WaoT = (half_t*)take((size_t)Lc * Hh * Hh * 2);
    half_t* WiT  = (half_t*)take((size_t)Lc * Hh * FF * 2);
    half_t* WoT  = (half_t*)take((size_t)Lc * FF * Hh * 2);
    half_t* xb   = (half_t*)take((size_t)M * Hh * 2);   // x fp16 / ctx fp16 (reused)
    half_t* Qb   = (half_t*)take((size_t)M * Hh * 2);
    half_t* Kb2  = (half_t*)take((size_t)M * Hh * 2);
    half_t* Vtb  = (half_t*)take((size_t)M * Hh * 2);
    (void)     take((size_t)M * Hh * 2);                // pad so h1 (=Qb) spans 32MB
    half_t* h1   = Qb;                                  // FFN hidden reuses dead Q/K/V
    float*  t0   = (float*)take((size_t)M * Hh * 4);
    float*  x1f  = (float*)take((size_t)M * Hh * 4);
    half_t* x1b  = (half_t*)take((size_t)M * Hh * 2);

    dim3 tb(256);

    for (int l = 0; l < Lc; l++) {
        transpose_cast<<<dim3(Hh/32, Hh/32), tb, 0, stream>>>(Wq  + (size_t)l*Hh*Hh, WqT  + (size_t)l*Hh*Hh, Hh, Hh);
        transpose_cast<<<dim3(Hh/32, Hh/32), tb, 0, stream>>>(Wk  + (size_t)l*Hh*Hh, WkT  + (size_t)l*Hh*Hh, Hh, Hh);
        transpose_cast<<<dim3(Hh/32, Hh/32), tb, 0, stream>>>(Wv  + (size_t)l*Hh*Hh, WvT  + (size_t)l*Hh*Hh, Hh, Hh);
        transpose_cast<<<dim3(Hh/32, Hh/32), tb, 0, stream>>>(Wao + (size_t)l*Hh*Hh, WaoT + (size_t)l*Hh*Hh, Hh, Hh);
        transpose_cast<<<dim3(FF/32, Hh/32), tb, 0, stream>>>(Wi  + (size_t)l*Hh*FF, WiT  + (size_t)l*Hh*FF, Hh, FF);
        transpose_cast<<<dim3(Hh/32, FF/32), tb, 0, stream>>>(Wo  + (size_t)l*FF*Hh, WoT  + (size_t)l*FF*Hh, FF, Hh);
    }
    cast_f32_f16<<<dim3(M * Hh / 1024), tb, 0, stream>>>(hs, xb);

    const float* xres = hs;
    for (int l = 0; l < Lc; l++) {
        const half_t* WqTl  = WqT  + (size_t)l * Hh * Hh;
        const half_t* WkTl  = WkT  + (size_t)l * Hh * Hh;
        const half_t* WvTl  = WvT  + (size_t)l * Hh * Hh;
        const half_t* WaoTl = WaoT + (size_t)l * Hh * Hh;
        const half_t* WiTl  = WiT  + (size_t)l * Hh * FF;
        const half_t* WoTl  = WoT  + (size_t)l * FF * Hh;

        gemm_bt<<<dim3(Hh/128, M/128), tb, 0, stream>>>(xb, WqTl, bq + l*Hh, nullptr, Qb,  M, Hh, Hh, MODE_H16);
        gemm_bt<<<dim3(Hh/128, M/128), tb, 0, stream>>>(xb, WkTl, bk + l*Hh, nullptr, Kb2, M, Hh, Hh, MODE_H16);
        gemm_bt<<<dim3(Hh/128, M/128), tb, 0, stream>>>(xb, WvTl, bv + l*Hh, nullptr, Vtb, M, Hh, Hh, MODE_VT);

        flash_attn<<<dim3(S/64, NH, Bb), tb, 0, stream>>>(Qb, Kb2, Vtb, mask, xb, S, Hh);

        gemm_bt<<<dim3(Hh/128, M/128), tb, 0, stream>>>(xb, WaoTl, bao + l*Hh, xres, t0, M, Hh, Hh, MODE_F32R);
        layernorm_k<<<dim3(M), tb, 0, stream>>>(t0, g1 + l*Hh, b1 + l*Hh, x1f, x1b);

        gemm_bt<<<dim3(FF/128, M/128), tb, 0, stream>>>(x1b, WiTl, bi + l*FF, nullptr, h1, M, FF, Hh, MODE_GELU);
        gemm_bt<<<dim3(Hh/128, M/128), tb, 0, stream>>>(h1,  WoTl, bo + l*Hh, x1f,    t0, M, Hh, FF, MODE_F32R);

        float* outf = (l == Lc - 1) ? (float*)d_out : x1f;
        layernorm_k<<<dim3(M), tb, 0, stream>>>(t0, g2 + l*Hh, b2 + l*Hh, outf, xb);
        xres = x1f;
    }
}